// Round 8
// baseline (327.942 us; speedup 1.0000x reference)
//
#include <hip/hip_runtime.h>
#include <cmath>

#define NN 50000
#define KK 15
#define DD 128
#define HH 64
#define NKE (NN * KK)

// register-file broadcast: readlane -> SGPR, feeds v_fma as the scalar operand
#define RLF(v, l) __uint_as_float(__builtin_amdgcn_readlane(__float_as_uint(v), (l)))

// ---------------------------------------------------------------------------
// kP3: fused 3-segment per-node GEMM via REGISTER broadcast.
//   XA = x @ ew1[0:128], XB = x @ ew1[128:256], XC = x @ dw1[0:128]
// Wave = 8 rows x 64 j-lanes.  x: 4 KB staged in 16 VGPRs via coalesced
// float4 loads (x[r][k] -> component k&3 of xs[r>>1], lane (r&1)*32 + k>>2).
// Broadcast = v_readlane (VALU-rate, no memory).  W: 12 lane-coalesced
// loads per k4 (96 KB, L1/L2-hot).  Stores lane-coalesced.
// Prior failures this replaces: LDS bcast (12cyc/16B), sK$ streaming
// (lgkmcnt(0) drains), uniform vector bcast (naked L1 latency).
// ---------------------------------------------------------------------------
__global__ __launch_bounds__(256, 4) void kP3(const float* __restrict__ x,
                                              const float* __restrict__ ew1,
                                              const float* __restrict__ dw1,
                                              float* __restrict__ ws) {
    int lane = threadIdx.x & 63;
    int wv = threadIdx.x >> 6;
    int r0 = blockIdx.x * 32 + wv * 8;       // 50000 % 8 == 0: wave-uniform guard
    if (r0 >= NN) return;

    const float4* xg = (const float4*)(x + (size_t)r0 * DD);
    float4 xs0 = xg[0 * 64 + lane];          // rows 0-1
    float4 xs1 = xg[1 * 64 + lane];          // rows 2-3
    float4 xs2 = xg[2 * 64 + lane];          // rows 4-5
    float4 xs3 = xg[3 * 64 + lane];          // rows 6-7

    const float* W0 = ew1;
    const float* W1 = ew1 + DD * HH;
    const float* W2 = dw1;

    float a0[8], a1[8], a2[8];
#pragma unroll
    for (int r = 0; r < 8; ++r) { a0[r] = 0.f; a1[r] = 0.f; a2[r] = 0.f; }

#pragma unroll 1
    for (int k4 = 0; k4 < DD / 4; ++k4) {
        float w00 = W0[(k4 * 4 + 0) * HH + lane];
        float w01 = W0[(k4 * 4 + 1) * HH + lane];
        float w02 = W0[(k4 * 4 + 2) * HH + lane];
        float w03 = W0[(k4 * 4 + 3) * HH + lane];
        float w10 = W1[(k4 * 4 + 0) * HH + lane];
        float w11 = W1[(k4 * 4 + 1) * HH + lane];
        float w12 = W1[(k4 * 4 + 2) * HH + lane];
        float w13 = W1[(k4 * 4 + 3) * HH + lane];
        float w20 = W2[(k4 * 4 + 0) * HH + lane];
        float w21 = W2[(k4 * 4 + 1) * HH + lane];
        float w22 = W2[(k4 * 4 + 2) * HH + lane];
        float w23 = W2[(k4 * 4 + 3) * HH + lane];
        int lsE = k4;                         // even rows live in lanes 0..31
        int lsO = 32 + k4;                    // odd rows in lanes 32..63

#define KP_ROW(r, S, L)                                                    \
        {                                                                  \
            float xk0 = RLF(S.x, L), xk1 = RLF(S.y, L);                    \
            float xk2 = RLF(S.z, L), xk3 = RLF(S.w, L);                    \
            a0[r] = fmaf(xk0, w00, a0[r]); a0[r] = fmaf(xk1, w01, a0[r]);  \
            a0[r] = fmaf(xk2, w02, a0[r]); a0[r] = fmaf(xk3, w03, a0[r]);  \
            a1[r] = fmaf(xk0, w10, a1[r]); a1[r] = fmaf(xk1, w11, a1[r]);  \
            a1[r] = fmaf(xk2, w12, a1[r]); a1[r] = fmaf(xk3, w13, a1[r]);  \
            a2[r] = fmaf(xk0, w20, a2[r]); a2[r] = fmaf(xk1, w21, a2[r]);  \
            a2[r] = fmaf(xk2, w22, a2[r]); a2[r] = fmaf(xk3, w23, a2[r]);  \
        }
        KP_ROW(0, xs0, lsE) KP_ROW(1, xs0, lsO)
        KP_ROW(2, xs1, lsE) KP_ROW(3, xs1, lsO)
        KP_ROW(4, xs2, lsE) KP_ROW(5, xs2, lsO)
        KP_ROW(6, xs3, lsE) KP_ROW(7, xs3, lsO)
#undef KP_ROW
    }
    float* o0 = ws + (size_t)r0 * HH + lane;
    float* o1 = ws + (size_t)NN * HH + (size_t)r0 * HH + lane;
    float* o2 = ws + 2 * (size_t)NN * HH + (size_t)r0 * HH + lane;
#pragma unroll
    for (int r = 0; r < 8; ++r) {
        o0[r * HH] = a0[r];
        o1[r * HH] = a1[r];
        o2[r * HH] = a2[r];
    }
}

// ---------------------------------------------------------------------------
// kE: thread-per-edge (FROZEN — best measured 93 us).
// ---------------------------------------------------------------------------
__global__ __launch_bounds__(128, 4) void kE(const int* __restrict__ srcIdx,
                                             const float* __restrict__ dist,
                                             const float* __restrict__ xabc,
                                             const float* __restrict__ ew1,
                                             const float* __restrict__ eb1,
                                             const float* __restrict__ ew2,
                                             const float* __restrict__ eb2,
                                             const float* __restrict__ ew3,
                                             const float* __restrict__ eb3,
                                             float* __restrict__ energy_out) {
    int e = blockIdx.x * 128 + threadIdx.x;
    if (e >= NKE) return;
    int s = srcIdx[e];
    int d = e / KK;
    float dd = dist[e];
    const float* A = xabc + (size_t)d * HH;
    const float* B = xabc + (size_t)NN * HH + (size_t)s * HH;
    const float* w1l = ew1 + 2 * DD * HH;

    float acc[HH];
#pragma unroll
    for (int j = 0; j < HH; ++j) acc[j] = 0.f;

    float4 a4 = *(const float4*)A;
    float4 bp0 = *(const float4*)B;
    float4 bp1 = *(const float4*)(B + 4);
#pragma unroll 1
    for (int i4 = 0; i4 < HH / 4; ++i4) {
        float4 a = a4, b = bp0;
        int n1 = (i4 + 1 < 16) ? (i4 + 1) : 15;
        int n2 = (i4 + 2 < 16) ? (i4 + 2) : 15;
        a4 = *(const float4*)(A + n1 * 4);
        bp0 = bp1;
        bp1 = *(const float4*)(B + n2 * 4);
        float h[4];
        h[0] = fmaxf(a.x + b.x + dd * w1l[i4 * 4 + 0] + eb1[i4 * 4 + 0], 0.f);
        h[1] = fmaxf(a.y + b.y + dd * w1l[i4 * 4 + 1] + eb1[i4 * 4 + 1], 0.f);
        h[2] = fmaxf(a.z + b.z + dd * w1l[i4 * 4 + 2] + eb1[i4 * 4 + 2], 0.f);
        h[3] = fmaxf(a.w + b.w + dd * w1l[i4 * 4 + 3] + eb1[i4 * 4 + 3], 0.f);
#pragma unroll
        for (int k = 0; k < 4; ++k) {
            const float* wr = ew2 + (i4 * 4 + k) * HH;
#pragma unroll
            for (int j4 = 0; j4 < 16; ++j4) {
                float4 w = *(const float4*)(wr + j4 * 4);
                acc[j4 * 4 + 0] = fmaf(h[k], w.x, acc[j4 * 4 + 0]);
                acc[j4 * 4 + 1] = fmaf(h[k], w.y, acc[j4 * 4 + 1]);
                acc[j4 * 4 + 2] = fmaf(h[k], w.z, acc[j4 * 4 + 2]);
                acc[j4 * 4 + 3] = fmaf(h[k], w.w, acc[j4 * 4 + 3]);
            }
        }
    }
    float lg = eb3[0];
#pragma unroll
    for (int j = 0; j < HH; ++j)
        lg = fmaf(fmaxf(acc[j] + eb2[j], 0.f), ew3[j], lg);
    energy_out[e] = 1.f / (1.f + expf(-2.f * lg));
}

// ---------------------------------------------------------------------------
// kF1: wave-per-node degree MLP -> k_cont.  Lane t holds dw2 column t in 64
// VGPRs (loaded once per wave, reused over ~16 nodes).  g broadcast via
// readlane.  All reduction orders replicate the prior passing rounds'
// exact fp32 rounding (sequential fmaf chains via paired readlanes).
// 3128 waves (vs 782-thread..wave starvation that made R7 kF ~100 us).
// ---------------------------------------------------------------------------
#define KF1_BLOCKS 782
__global__ __launch_bounds__(256, 4) void kF1(const float* __restrict__ xabc,
                                              const float* __restrict__ dw1,
                                              const float* __restrict__ db1,
                                              const float* __restrict__ dw2,
                                              const float* __restrict__ db2,
                                              const float* __restrict__ dw3,
                                              const float* __restrict__ db3,
                                              float* __restrict__ out) {
    int lane = threadIdx.x & 63;
    int wgid = blockIdx.x * 4 + (threadIdx.x >> 6);
    const int nwaves = KF1_BLOCKS * 4;
    const float* energy = out + 2 * (size_t)NKE;
    const float* XC = xabc + 2 * (size_t)NN * HH;

    float w2col[HH];
#pragma unroll
    for (int j = 0; j < HH; ++j) w2col[j] = dw2[j * HH + lane];
    float w1l_l = dw1[DD * HH + lane];
    float db1_l = db1[lane];
    float db2_l = db2[lane];
    float dw3_l = dw3[lane];
    float db3s = db3[0];

#pragma unroll 1
    for (int n = wgid; n < NN; n += nwaves) {
        float ev = 0.f;
        if (lane < KK) ev = energy[(size_t)n * KK + lane];
        // dh: sequential adds j=0..14 (matches prior rounds' order)
        float dh = 0.f;
#pragma unroll
        for (int j = 0; j < KK; ++j) dh += RLF(ev, j);
        // layer 1 (lane = hidden unit)
        float g = fmaxf(XC[(size_t)n * HH + lane] + dh * w1l_l + db1_l, 0.f);
        // layer 2 (lane = output unit t): acc_t = sum_j g_j * dw2[j][t],
        // ascending j, fmaf — identical rounding to prior rounds
        float acc = 0.f;
#pragma unroll
        for (int j = 0; j < HH; ++j)
            acc = fmaf(RLF(g, j), w2col[j], acc);
        // layer 3: kraw = db3 + sum_t relu(acc_t+db2_t)*dw3_t, sequential fmaf
        float tv = fmaxf(acc + db2_l, 0.f);
        float kraw = db3s;
#pragma unroll
        for (int t = 0; t < HH; ++t)
            kraw = fmaf(RLF(tv, t), RLF(dw3_l, t), kraw);
        float kcont = 2.f + 13.f / (1.f + expf(-kraw));
        if (lane == 0) out[3 * (size_t)NKE + n] = kcont;
    }
}

// ---------------------------------------------------------------------------
// kG: thread-per-node sort/gate epilogue (light — no MLP latency chains).
// Register Batcher-16 sort (energy desc, idx asc), hard top-k gate,
// normalize, scatter.  Identical math to prior rounds' kF epilogue.
// ---------------------------------------------------------------------------
__global__ __launch_bounds__(256, 4) void kG(float* __restrict__ out) {
    int n = blockIdx.x * 256 + threadIdx.x;
    if (n >= NN) return;
    const float* energy = out + 2 * (size_t)NKE;

    float ev[KK];
#pragma unroll
    for (int j = 0; j < KK; ++j) ev[j] = energy[(size_t)n * KK + j];
    float kcont = out[3 * (size_t)NKE + n];

    float se[16];
    int si[16];
#pragma unroll
    for (int j = 0; j < KK; ++j) { se[j] = ev[j]; si[j] = j; }
    se[15] = -1.f; si[15] = 15;

#pragma unroll
    for (int p = 1; p < 16; p <<= 1) {
#pragma unroll
        for (int k = p; k >= 1; k >>= 1) {
#pragma unroll
            for (int j = k & (p - 1); j + k < 16; j += 2 * k) {
#pragma unroll
                for (int i = 0; i < k; ++i) {
                    int a = i + j, b = i + j + k;
                    if (b < 16 && (a / (2 * p)) == (b / (2 * p))) {
                        bool sw = (se[b] > se[a]) ||
                                  (se[b] == se[a] && si[b] < si[a]);
                        float ea = sw ? se[b] : se[a];
                        float eb = sw ? se[a] : se[b];
                        int ia = sw ? si[b] : si[a];
                        int ib = sw ? si[a] : si[b];
                        se[a] = ea; se[b] = eb; si[a] = ia; si[b] = ib;
                    }
                }
            }
        }
    }

    float kint = rintf(kcont);
    kint = fminf(fmaxf(kint, 2.f), 15.f);

    float wsrt[KK];
    float denom = 0.f;
#pragma unroll
    for (int r = 0; r < KK; ++r) {
        float sel = ((float)(r + 1) <= kint) ? 1.f : 0.f;
        float wvv = se[r] * sel;
        wsrt[r] = wvv;
        denom += wvv;
    }
    denom = fmaxf(denom, 1e-12f);

#pragma unroll
    for (int r = 0; r < KK; ++r) {
        float sel = ((float)(r + 1) <= kint) ? 1.f : 0.f;
        int j0 = si[r];
        out[(size_t)NKE + (size_t)n * KK + j0] = sel;     // edge_gate
        out[(size_t)n * KK + j0] = wsrt[r] / denom;       // edge_weight
    }
}

extern "C" void kernel_launch(void* const* d_in, const int* in_sizes, int n_in,
                              void* d_out, int out_size, void* d_ws, size_t ws_size,
                              hipStream_t stream) {
    const float* x   = (const float*)d_in[0];
    const int*   ei  = (const int*)d_in[1];
    const float* ed  = (const float*)d_in[2];
    const float* ew1 = (const float*)d_in[3];
    const float* eb1 = (const float*)d_in[4];
    const float* ew2 = (const float*)d_in[5];
    const float* eb2 = (const float*)d_in[6];
    const float* ew3 = (const float*)d_in[7];
    const float* eb3 = (const float*)d_in[8];
    const float* dw1 = (const float*)d_in[9];
    const float* db1 = (const float*)d_in[10];
    const float* dw2 = (const float*)d_in[11];
    const float* db2 = (const float*)d_in[12];
    const float* dw3 = (const float*)d_in[13];
    const float* db3 = (const float*)d_in[14];
    float* out = (float*)d_out;
    float* ws  = (float*)d_ws;

    hipLaunchKernelGGL(kP3, dim3((NN + 31) / 32), dim3(256), 0, stream,
                       x, ew1, dw1, ws);
    hipLaunchKernelGGL(kE, dim3((NKE + 127) / 128), dim3(128), 0, stream,
                       ei, ed, ws, ew1, eb1, ew2, eb2, ew3, eb3,
                       out + 2 * (size_t)NKE);
    hipLaunchKernelGGL(kF1, dim3(KF1_BLOCKS), dim3(256), 0, stream,
                       ws, dw1, db1, dw2, db2, dw3, db3, out);
    hipLaunchKernelGGL(kG, dim3((NN + 255) / 256), dim3(256), 0, stream, out);
}